// Round 9
// baseline (410.008 us; speedup 1.0000x reference)
//
#include <hip/hip_runtime.h>

// GraphAttentionLayer, MI355X (gfx950). All fp32 in/out.
// out = 0.5 * softmax_row(cos(xn,yn) + (1-adj)*NEG) @ y + 0.5 * x
//
// R9 = R8 (dense flash-MFMA, verified) with the adj path restructured:
// tiles processed in PAIRS; lane (hi,lm) reads the full 256B row-slice of
// row lm, tile 2tp+hi (16 x float4, one aligned 256B burst -> adj fetched
// exactly once), packs 64 bits locally (no ballot), shfl_xor(32) swaps
// masks across the hi halves. The pair's adj loads are issued one FULL
// PAIR ahead (A[16] regs) -> ~16KB in flight per wave -> HBM saturation.

typedef short bf16x8 __attribute__((ext_vector_type(8)));
typedef float f32x16 __attribute__((ext_vector_type(16)));

static constexpr float EPSF = 1e-8f;
static constexpr float LOG2E = 1.44269504088896340736f;

__device__ __forceinline__ unsigned short f2bf(float f) {
    union { float f; unsigned int i; } v; v.f = f;
    return (unsigned short)((v.i + 0x7FFFu + ((v.i >> 16) & 1u)) >> 16);
}

// ---------- prepass: xhat (plain row-major normalized bf16) ----------
__global__ __launch_bounds__(256) void prep_x(const float* __restrict__ x,
                                              unsigned short* __restrict__ xhat, int N) {
    int row = (int)((blockIdx.x * blockDim.x + threadIdx.x) >> 6);
    int lane = threadIdx.x & 63;
    if (row >= N) return;
    float4 v = *(const float4*)(x + (size_t)row * 256 + lane * 4);
    float ss = v.x * v.x + v.y * v.y + v.z * v.z + v.w * v.w;
#pragma unroll
    for (int o = 1; o < 64; o <<= 1) ss += __shfl_xor(ss, o, 64);
    float inv = 1.0f / fmaxf(sqrtf(ss), EPSF);
    ushort4 b = { f2bf(v.x * inv), f2bf(v.y * inv), f2bf(v.z * inv), f2bf(v.w * inv) };
    *(ushort4*)(xhat + (size_t)row * 256 + lane * 4) = b;
}

// ---------- prepass: yswz (normalized, tiled+swizzled for QK^T A-frags) ----
__global__ __launch_bounds__(256) void prep_y(const float* __restrict__ y,
                                              char* __restrict__ yswz, int M) {
    int row = (int)((blockIdx.x * blockDim.x + threadIdx.x) >> 6);
    int lane = threadIdx.x & 63;
    if (row >= M) return;
    float4 v = *(const float4*)(y + (size_t)row * 256 + lane * 4);
    float ss = v.x * v.x + v.y * v.y + v.z * v.z + v.w * v.w;
#pragma unroll
    for (int o = 1; o < 64; o <<= 1) ss += __shfl_xor(ss, o, 64);
    float inv = 1.0f / fmaxf(sqrtf(ss), EPSF);
    int jt = row >> 6, r = row & 63;
    int u = lane >> 1, h = lane & 1;           // lane's float4 = half-unit (u,h)
    int phys = u ^ (r & 31);
    ushort4 b = { f2bf(v.x * inv), f2bf(v.y * inv), f2bf(v.z * inv), f2bf(v.w * inv) };
    *(ushort4*)(yswz + (size_t)jt * 32768 + r * 512 + phys * 16 + h * 8) = b;
}

// ---------- prepass: ytswz = bf16(y^T), [jtile][256 n][8 units] swizzled ----
__global__ __launch_bounds__(256) void prep_yt(const float* __restrict__ y,
                                               char* __restrict__ ytswz, int M) {
    int t = blockIdx.x * blockDim.x + threadIdx.x;
    int np = t & 255;
    int up = (t >> 8) & 7;
    int jt = t >> 11;
    if (jt >= (M >> 6)) return;
    const float* yb = y + (size_t)(jt * 64 + up * 8) * 256 + np;
    unsigned w0 = (unsigned)f2bf(yb[0])        | ((unsigned)f2bf(yb[256])  << 16);
    unsigned w1 = (unsigned)f2bf(yb[512])      | ((unsigned)f2bf(yb[768])  << 16);
    unsigned w2 = (unsigned)f2bf(yb[1024])     | ((unsigned)f2bf(yb[1280]) << 16);
    unsigned w3 = (unsigned)f2bf(yb[1536])     | ((unsigned)f2bf(yb[1792]) << 16);
    uint4 out = { w0, w1, w2, w3 };
    *(uint4*)(ytswz + (size_t)jt * 32768 + np * 128 + ((up ^ (np & 7)) << 4)) = out;
}

// ---------- main ----------
#define GLD16(gp, lp) __builtin_amdgcn_global_load_lds( \
    (const __attribute__((address_space(1))) unsigned int*)(gp), \
    (__attribute__((address_space(3))) unsigned int*)(lp), 16, 0, 0)

#define PKSWAP(E, TAU, W) { \
    unsigned X0, X1, Y0, Y1; \
    asm("v_cvt_pk_bf16_f32 %0, %1, %2" : "=v"(X0) : "v"(E[8*TAU+0]), "v"(E[8*TAU+1])); \
    asm("v_cvt_pk_bf16_f32 %0, %1, %2" : "=v"(X1) : "v"(E[8*TAU+2]), "v"(E[8*TAU+3])); \
    asm("v_cvt_pk_bf16_f32 %0, %1, %2" : "=v"(Y0) : "v"(E[8*TAU+4]), "v"(E[8*TAU+5])); \
    asm("v_cvt_pk_bf16_f32 %0, %1, %2" : "=v"(Y1) : "v"(E[8*TAU+6]), "v"(E[8*TAU+7])); \
    asm("v_permlane32_swap_b32 %0, %1" : "+v"(X0), "+v"(Y0)); \
    asm("v_permlane32_swap_b32 %0, %1" : "+v"(X1), "+v"(Y1)); \
    W[0] = X0; W[1] = X1; W[2] = Y0; W[3] = Y1; }

__global__ __launch_bounds__(512, 2) void gat_main(
        const unsigned short* __restrict__ xhat,
        const char* __restrict__ yswz,
        const char* __restrict__ ytswz,
        const float* __restrict__ adj,
        float* __restrict__ o0,     // jc==0 partial (d_out)
        float* __restrict__ ows,    // jc>=1 partials
        float* __restrict__ zpart,
        int N, int M, int TPB) {
    __shared__ __align__(16) char lds[131072];  // Y dbuf 2x32K | Yt dbuf 2x32K

    int tid = threadIdx.x;
    int w = tid >> 6, lane = tid & 63;
    int hi = lane >> 5, lm = lane & 31;
    int i0 = (int)blockIdx.x * 256;
    int jc = (int)blockIdx.y;
    int g0 = jc * TPB;

    // Q-frags: lane holds xhat[i0+w*32+lm][16*kt + 8*hi + 0..7]
    bf16x8 qf[16];
    {
        const char* qb = (const char*)xhat + (size_t)(i0 + w * 32 + lm) * 512 + hi * 16;
#pragma unroll
        for (int kt = 0; kt < 16; ++kt) qf[kt] = *(const bf16x8*)(qb + kt * 32);
    }

    f32x16 o[8];
#pragma unroll
    for (int nt = 0; nt < 8; ++nt) o[nt] = (f32x16)(0.0f);
    float z = 0.0f;

    // stage tile g into buffer b (linear LDS; source pre-swizzled)
    auto stage = [&](int g, int b) {
        const char* ys = yswz + (size_t)g * 32768;
        const char* ts = ytswz + (size_t)g * 32768;
        char* yd = lds + b * 32768;
        char* td = lds + 65536 + b * 32768;
#pragma unroll
        for (int c = 0; c < 4; ++c) {
            int lo = w * 4096 + c * 1024;        // wave-uniform LDS base
            int go = lo + lane * 16;             // per-lane global addr
            GLD16(ys + go, yd + lo);
            GLD16(ts + go, td + lo);
        }
    };

    // adj: lane (hi,lm) streams the full 256B row-slice of row lm, tile 2tp+hi
    const float* arowbase = adj + (size_t)(i0 + w * 32 + lm) * M;
    float4 A[16];
    auto loadA = [&](int tp) {
        int tt = 2 * tp + hi;
        if (tt > TPB - 1) tt = TPB - 1;
        const float* ab = arowbase + (size_t)(g0 + tt) * 64;
#pragma unroll
        for (int q = 0; q < 16; ++q) A[q] = *(const float4*)(ab + q * 4);
    };
    auto packA = [&]() -> unsigned long long {
        unsigned long long m = 0ull;
#pragma unroll
        for (int q = 0; q < 16; ++q) {
            unsigned b = (A[q].x != 0.0f ? 1u : 0u) | (A[q].y != 0.0f ? 2u : 0u)
                       | (A[q].z != 0.0f ? 4u : 0u) | (A[q].w != 0.0f ? 8u : 0u);
            m |= (unsigned long long)b << (4 * q);
        }
        return m;
    };

    loadA(0);
    stage(g0, 0);
    __syncthreads();

    int npair = (TPB + 1) >> 1;
    for (int tp = 0; tp < npair; ++tp) {
        unsigned long long own = packA();          // masks for tile 2tp+hi, row lm
        if (tp + 1 < npair) loadA(tp + 1);         // in flight across both tiles
        unsigned long long oth = __shfl_xor(own, 32, 64);

#pragma unroll
        for (int h = 0; h < 2; ++h) {
            int t = 2 * tp + h;
            if (t >= TPB) break;
            int buf = t & 1;
            const char* yb = lds + buf * 32768;

            // full 64-bit mask for row lm of tile t
            unsigned long long m64 = (h == 0) ? (hi ? oth : own)
                                              : (hi ? own : oth);
            unsigned mw0 = (unsigned)m64, mw1 = (unsigned)(m64 >> 32);

            // QK^T (swapped): S^T[jt*32+crow][lm] over K=256
            f32x16 s0 = (f32x16)(0.0f), s1 = (f32x16)(0.0f);
#pragma unroll
            for (int kt = 0; kt < 16; ++kt) {
                int phys = (hi + 2 * kt) ^ lm;
                bf16x8 a0 = *(const bf16x8*)(yb + lm * 512 + phys * 16);
                bf16x8 a1 = *(const bf16x8*)(yb + (32 + lm) * 512 + phys * 16);
                s0 = __builtin_amdgcn_mfma_f32_32x32x16_bf16(a0, qf[kt], s0, 0, 0, 0);
                s1 = __builtin_amdgcn_mfma_f32_32x32x16_bf16(a1, qf[kt], s1, 0, 0, 0);
            }

            // mask + exp(cos-1) + Z, in place into s0/s1
            float zl = 0.0f;
#pragma unroll
            for (int rg = 0; rg < 16; ++rg) {
                int jl = (rg & 3) + 8 * (rg >> 2) + 4 * hi;
                float x0 = __builtin_exp2f(__builtin_fmaf(s0[rg], LOG2E, -LOG2E));
                float x1 = __builtin_exp2f(__builtin_fmaf(s1[rg], LOG2E, -LOG2E));
                s0[rg] = ((mw0 >> jl) & 1u) ? x0 : 0.0f;
                s1[rg] = ((mw1 >> jl) & 1u) ? x1 : 0.0f;
                zl += s0[rg] + s1[rg];
            }
            z += zl;

            // P -> PV A-frags in-register (cvt_pk + permlane32_swap)
            unsigned pw0[4], pw1[4], pw2[4], pw3[4];
            PKSWAP(s0, 0, pw0); PKSWAP(s0, 1, pw1);
            PKSWAP(s1, 0, pw2); PKSWAP(s1, 1, pw3);
            bf16x8 paf[4];
            { uint4 q = { pw0[0], pw0[1], pw0[2], pw0[3] }; paf[0] = __builtin_bit_cast(bf16x8, q); }
            { uint4 q = { pw1[0], pw1[1], pw1[2], pw1[3] }; paf[1] = __builtin_bit_cast(bf16x8, q); }
            { uint4 q = { pw2[0], pw2[1], pw2[2], pw2[3] }; paf[2] = __builtin_bit_cast(bf16x8, q); }
            { uint4 q = { pw3[0], pw3[1], pw3[2], pw3[3] }; paf[3] = __builtin_bit_cast(bf16x8, q); }

            // stage next tile: end-of-iter barrier drain only covers PV
            if (t + 1 < TPB) stage(g0 + t + 1, buf ^ 1);

            // PV: O[m][n'] += P[m][k'] * yT[n'][k']
            const char* tb = lds + 65536 + buf * 32768;
#pragma unroll
            for (int nt = 0; nt < 8; ++nt) {
                int np = nt * 32 + lm;
#pragma unroll
                for (int tpq = 0; tpq < 4; ++tpq) {
                    int phys = (hi + 2 * tpq) ^ (np & 7);
                    bf16x8 bfr = *(const bf16x8*)(tb + np * 128 + phys * 16);
                    o[nt] = __builtin_amdgcn_mfma_f32_32x32x16_bf16(paf[tpq], bfr, o[nt], 0, 0, 0);
                }
            }

            __syncthreads();
        }
    }

    // Z partial (lane pair hi/lo holds complementary j subsets)
    z += __shfl_xor(z, 32, 64);
    if (lane < 32) zpart[(size_t)jc * N + i0 + w * 32 + lane] = z;

    float* ob = (jc == 0) ? o0 : (ows + (size_t)(jc - 1) * N * 256);
#pragma unroll
    for (int nt = 0; nt < 8; ++nt) {
#pragma unroll
        for (int rg = 0; rg < 16; ++rg) {
            int m = (rg & 3) + 8 * (rg >> 2) + 4 * hi;
            ob[(size_t)(i0 + w * 32 + m) * 256 + nt * 32 + lm] = o[nt][rg];
        }
    }
}

// ---------- reductions ----------
__global__ __launch_bounds__(256) void zred(const float* __restrict__ zpart,
                                            float* __restrict__ zinv, int N, int js) {
    int i = blockIdx.x * 256 + threadIdx.x;
    if (i >= N) return;
    float s = 0.0f;
    for (int jc = 0; jc < js; ++jc) s += zpart[(size_t)jc * N + i];
    zinv[i] = 0.5f / s;
}

__global__ __launch_bounds__(256) void fin(float* __restrict__ out,
                                           const float* __restrict__ ows,
                                           const float* __restrict__ zinv,
                                           const float* __restrict__ x,
                                           int N, int js) {
    int gid = blockIdx.x * 256 + threadIdx.x;     // one float4 each
    if (gid >= N * 64) return;
    int i = gid >> 6;
    float4 a = ((const float4*)out)[gid];
    for (int jc = 1; jc < js; ++jc) {
        float4 p = ((const float4*)(ows + (size_t)(jc - 1) * N * 256))[gid];
        a.x += p.x; a.y += p.y; a.z += p.z; a.w += p.w;
    }
    float zi = zinv[i];
    float4 xv = ((const float4*)x)[gid];
    float4 r;
    r.x = a.x * zi + 0.5f * xv.x;
    r.y = a.y * zi + 0.5f * xv.y;
    r.z = a.z * zi + 0.5f * xv.z;
    r.w = a.w * zi + 0.5f * xv.w;
    ((float4*)out)[gid] = r;
}

extern "C" void kernel_launch(void* const* d_in, const int* in_sizes, int n_in,
                              void* d_out, int out_size, void* d_ws, size_t ws_size,
                              hipStream_t stream) {
    const float* x = (const float*)d_in[0];
    const float* y = (const float*)d_in[1];
    const float* adj = (const float*)d_in[2];
    float* out = (float*)d_out;

    const int D = 256;
    int N = in_sizes[0] / D;
    int M = in_sizes[1] / D;

    char* w = (char*)d_ws;
    unsigned short* xhat = (unsigned short*)w;                       // N*512 B
    char* yswz  = w + (size_t)N * 512;                               // M*512 B
    char* ytswz = w + (size_t)N * 512 + (size_t)M * 512;             // M*512 B
    size_t base = (size_t)N * 512 + 2 * (size_t)M * 512;

    int js = 1;
    {
        int cands[3] = { 8, 4, 2 };
        for (int k = 0; k < 3; ++k) {
            int c = cands[k];
            size_t need = base + (size_t)(c + 1) * N * 4 +           // zpart + zinv
                          (size_t)(c - 1) * N * 1024;                // O partials
            if (ws_size >= need) { js = c; break; }
        }
    }
    float* zpart = (float*)(w + base);
    float* zinv  = zpart + (size_t)js * N;
    float* ows   = zinv + N;
    int TPB = (M / 64) / js;

    prep_x<<<(N + 3) / 4, 256, 0, stream>>>(x, xhat, N);
    prep_y<<<(M + 3) / 4, 256, 0, stream>>>(y, yswz, M);
    prep_yt<<<((M / 64) * 2048 + 255) / 256, 256, 0, stream>>>(y, ytswz, M);
    gat_main<<<dim3(N / 256, js), 512, 0, stream>>>(xhat, yswz, ytswz, adj,
                                                    out, ows, zpart, N, M, TPB);
    zred<<<(N + 255) / 256, 256, 0, stream>>>(zpart, zinv, N, js);
    fin<<<(N * 64 + 255) / 256, 256, 0, stream>>>(out, ows, zinv, x, N, js);
}

// Round 10
// 233.622 us; speedup vs baseline: 1.7550x; 1.7550x over previous
//
#include <hip/hip_runtime.h>

// GraphAttentionLayer, MI355X (gfx950). All fp32 in/out.
// out = 0.5 * softmax_row(cos(xn,yn) + (1-adj)*NEG) @ y + 0.5 * x
//
// R10 = R8's verified dense flash-MFMA skeleton, with the adj stream moved
// into a dedicated BITMASK PREPASS:
//   prep_mask: adj[N,M] fp32 -> msk[N,M/16] u16 (1 bit/entry). Pure stream,
//   64B/lane coalesced, no cross-lane ops -> HBM roofline (~45us for 256MB).
//   gat_main: reads one u64 mask per (row, 64-col tile) from the 8MB mask
//   array (L2/L3-resident) -> no adj registers, no spill, no overfetch.
// R9's in-register adj pair-ahead (A[16]) spilled to scratch: +256MB fetch,
// +170MB write. This removes that entirely.

typedef short bf16x8 __attribute__((ext_vector_type(8)));
typedef float f32x16 __attribute__((ext_vector_type(16)));

static constexpr float EPSF = 1e-8f;
static constexpr float LOG2E = 1.44269504088896340736f;

__device__ __forceinline__ unsigned short f2bf(float f) {
    union { float f; unsigned int i; } v; v.f = f;
    return (unsigned short)((v.i + 0x7FFFu + ((v.i >> 16) & 1u)) >> 16);
}

// ---------- prepass: adj -> 1-bit masks (u16 per 16 cols) ----------
__global__ __launch_bounds__(256) void prep_mask(const float* __restrict__ adj,
                                                 unsigned short* __restrict__ msk,
                                                 long long total) {  // N*M/16
    long long stride = (long long)gridDim.x * blockDim.x;
    for (long long it = (long long)blockIdx.x * blockDim.x + threadIdx.x;
         it < total; it += stride) {
        const float* ap = adj + it * 16;
        float4 a0 = *(const float4*)(ap + 0);
        float4 a1 = *(const float4*)(ap + 4);
        float4 a2 = *(const float4*)(ap + 8);
        float4 a3 = *(const float4*)(ap + 12);
        unsigned m = 0;
        m |= (a0.x != 0.0f ? 1u : 0u) << 0;  m |= (a0.y != 0.0f ? 1u : 0u) << 1;
        m |= (a0.z != 0.0f ? 1u : 0u) << 2;  m |= (a0.w != 0.0f ? 1u : 0u) << 3;
        m |= (a1.x != 0.0f ? 1u : 0u) << 4;  m |= (a1.y != 0.0f ? 1u : 0u) << 5;
        m |= (a1.z != 0.0f ? 1u : 0u) << 6;  m |= (a1.w != 0.0f ? 1u : 0u) << 7;
        m |= (a2.x != 0.0f ? 1u : 0u) << 8;  m |= (a2.y != 0.0f ? 1u : 0u) << 9;
        m |= (a2.z != 0.0f ? 1u : 0u) << 10; m |= (a2.w != 0.0f ? 1u : 0u) << 11;
        m |= (a3.x != 0.0f ? 1u : 0u) << 12; m |= (a3.y != 0.0f ? 1u : 0u) << 13;
        m |= (a3.z != 0.0f ? 1u : 0u) << 14; m |= (a3.w != 0.0f ? 1u : 0u) << 15;
        msk[it] = (unsigned short)m;
    }
}

// ---------- prepass: xhat (plain row-major normalized bf16) ----------
__global__ __launch_bounds__(256) void prep_x(const float* __restrict__ x,
                                              unsigned short* __restrict__ xhat, int N) {
    int row = (int)((blockIdx.x * blockDim.x + threadIdx.x) >> 6);
    int lane = threadIdx.x & 63;
    if (row >= N) return;
    float4 v = *(const float4*)(x + (size_t)row * 256 + lane * 4);
    float ss = v.x * v.x + v.y * v.y + v.z * v.z + v.w * v.w;
#pragma unroll
    for (int o = 1; o < 64; o <<= 1) ss += __shfl_xor(ss, o, 64);
    float inv = 1.0f / fmaxf(sqrtf(ss), EPSF);
    ushort4 b = { f2bf(v.x * inv), f2bf(v.y * inv), f2bf(v.z * inv), f2bf(v.w * inv) };
    *(ushort4*)(xhat + (size_t)row * 256 + lane * 4) = b;
}

// ---------- prepass: yswz (normalized, tiled+swizzled for QK^T A-frags) ----
__global__ __launch_bounds__(256) void prep_y(const float* __restrict__ y,
                                              char* __restrict__ yswz, int M) {
    int row = (int)((blockIdx.x * blockDim.x + threadIdx.x) >> 6);
    int lane = threadIdx.x & 63;
    if (row >= M) return;
    float4 v = *(const float4*)(y + (size_t)row * 256 + lane * 4);
    float ss = v.x * v.x + v.y * v.y + v.z * v.z + v.w * v.w;
#pragma unroll
    for (int o = 1; o < 64; o <<= 1) ss += __shfl_xor(ss, o, 64);
    float inv = 1.0f / fmaxf(sqrtf(ss), EPSF);
    int jt = row >> 6, r = row & 63;
    int u = lane >> 1, h = lane & 1;           // lane's float4 = half-unit (u,h)
    int phys = u ^ (r & 31);
    ushort4 b = { f2bf(v.x * inv), f2bf(v.y * inv), f2bf(v.z * inv), f2bf(v.w * inv) };
    *(ushort4*)(yswz + (size_t)jt * 32768 + r * 512 + phys * 16 + h * 8) = b;
}

// ---------- prepass: ytswz = bf16(y^T), [jtile][256 n][8 units] swizzled ----
__global__ __launch_bounds__(256) void prep_yt(const float* __restrict__ y,
                                               char* __restrict__ ytswz, int M) {
    int t = blockIdx.x * blockDim.x + threadIdx.x;
    int np = t & 255;
    int up = (t >> 8) & 7;
    int jt = t >> 11;
    if (jt >= (M >> 6)) return;
    const float* yb = y + (size_t)(jt * 64 + up * 8) * 256 + np;
    unsigned w0 = (unsigned)f2bf(yb[0])        | ((unsigned)f2bf(yb[256])  << 16);
    unsigned w1 = (unsigned)f2bf(yb[512])      | ((unsigned)f2bf(yb[768])  << 16);
    unsigned w2 = (unsigned)f2bf(yb[1024])     | ((unsigned)f2bf(yb[1280]) << 16);
    unsigned w3 = (unsigned)f2bf(yb[1536])     | ((unsigned)f2bf(yb[1792]) << 16);
    uint4 out = { w0, w1, w2, w3 };
    *(uint4*)(ytswz + (size_t)jt * 32768 + np * 128 + ((up ^ (np & 7)) << 4)) = out;
}

// ---------- main ----------
#define GLD16(gp, lp) __builtin_amdgcn_global_load_lds( \
    (const __attribute__((address_space(1))) unsigned int*)(gp), \
    (__attribute__((address_space(3))) unsigned int*)(lp), 16, 0, 0)

#define PKSWAP(E, TAU, W) { \
    unsigned X0, X1, Y0, Y1; \
    asm("v_cvt_pk_bf16_f32 %0, %1, %2" : "=v"(X0) : "v"(E[8*TAU+0]), "v"(E[8*TAU+1])); \
    asm("v_cvt_pk_bf16_f32 %0, %1, %2" : "=v"(X1) : "v"(E[8*TAU+2]), "v"(E[8*TAU+3])); \
    asm("v_cvt_pk_bf16_f32 %0, %1, %2" : "=v"(Y0) : "v"(E[8*TAU+4]), "v"(E[8*TAU+5])); \
    asm("v_cvt_pk_bf16_f32 %0, %1, %2" : "=v"(Y1) : "v"(E[8*TAU+6]), "v"(E[8*TAU+7])); \
    asm("v_permlane32_swap_b32 %0, %1" : "+v"(X0), "+v"(Y0)); \
    asm("v_permlane32_swap_b32 %0, %1" : "+v"(X1), "+v"(Y1)); \
    W[0] = X0; W[1] = X1; W[2] = Y0; W[3] = Y1; }

__global__ __launch_bounds__(512, 2) void gat_main(
        const unsigned short* __restrict__ xhat,
        const char* __restrict__ yswz,
        const char* __restrict__ ytswz,
        const unsigned long long* __restrict__ mask64,  // [N][M/64]
        float* __restrict__ o0,     // jc==0 partial (d_out)
        float* __restrict__ ows,    // jc>=1 partials
        float* __restrict__ zpart,
        int N, int M, int TPB) {
    __shared__ __align__(16) char lds[131072];  // Y dbuf 2x32K | Yt dbuf 2x32K

    int tid = threadIdx.x;
    int w = tid >> 6, lane = tid & 63;
    int hi = lane >> 5, lm = lane & 31;
    int i0 = (int)blockIdx.x * 256;
    int jc = (int)blockIdx.y;
    int g0 = jc * TPB;

    // Q-frags: lane holds xhat[i0+w*32+lm][16*kt + 8*hi + 0..7]
    bf16x8 qf[16];
    {
        const char* qb = (const char*)xhat + (size_t)(i0 + w * 32 + lm) * 512 + hi * 16;
#pragma unroll
        for (int kt = 0; kt < 16; ++kt) qf[kt] = *(const bf16x8*)(qb + kt * 32);
    }

    f32x16 o[8];
#pragma unroll
    for (int nt = 0; nt < 8; ++nt) o[nt] = (f32x16)(0.0f);
    float z = 0.0f;

    // stage tile g into buffer b (linear LDS; source pre-swizzled)
    auto stage = [&](int g, int b) {
        const char* ys = yswz + (size_t)g * 32768;
        const char* ts = ytswz + (size_t)g * 32768;
        char* yd = lds + b * 32768;
        char* td = lds + 65536 + b * 32768;
#pragma unroll
        for (int c = 0; c < 4; ++c) {
            int lo = w * 4096 + c * 1024;        // wave-uniform LDS base
            int go = lo + lane * 16;             // per-lane global addr
            GLD16(ys + go, yd + lo);
            GLD16(ts + go, td + lo);
        }
    };

    stage(g0, 0);
    __syncthreads();

    // per-lane mask row: output row (i0 + w*32 + lm); both hi halves same row
    const unsigned long long* mrow = mask64 + (size_t)(i0 + w * 32 + lm) * (M >> 6) + g0;

    for (int t = 0; t < TPB; ++t) {
        int buf = t & 1;
        const char* yb = lds + buf * 32768;

        // issue mask load early; ~200cyc L2 latency hides under QK^T
        unsigned long long m64 = mrow[t];

        // QK^T (swapped): S^T[y-row][x-row] over K=256
        f32x16 s0 = (f32x16)(0.0f), s1 = (f32x16)(0.0f);
#pragma unroll
        for (int kt = 0; kt < 16; ++kt) {
            int phys = (hi + 2 * kt) ^ lm;
            bf16x8 a0 = *(const bf16x8*)(yb + lm * 512 + phys * 16);
            bf16x8 a1 = *(const bf16x8*)(yb + (32 + lm) * 512 + phys * 16);
            s0 = __builtin_amdgcn_mfma_f32_32x32x16_bf16(a0, qf[kt], s0, 0, 0, 0);
            s1 = __builtin_amdgcn_mfma_f32_32x32x16_bf16(a1, qf[kt], s1, 0, 0, 0);
        }

        unsigned mw0 = (unsigned)m64, mw1 = (unsigned)(m64 >> 32);

        // mask + exp(cos-1) + Z, in place into s0/s1
        float zl = 0.0f;
#pragma unroll
        for (int rg = 0; rg < 16; ++rg) {
            int jl = (rg & 3) + 8 * (rg >> 2) + 4 * hi;
            float x0 = __builtin_exp2f(__builtin_fmaf(s0[rg], LOG2E, -LOG2E));
            float x1 = __builtin_exp2f(__builtin_fmaf(s1[rg], LOG2E, -LOG2E));
            s0[rg] = ((mw0 >> jl) & 1u) ? x0 : 0.0f;
            s1[rg] = ((mw1 >> jl) & 1u) ? x1 : 0.0f;
            zl += s0[rg] + s1[rg];
        }
        z += zl;

        // P -> PV A-frags in-register (cvt_pk + permlane32_swap)
        unsigned pw0[4], pw1[4], pw2[4], pw3[4];
        PKSWAP(s0, 0, pw0); PKSWAP(s0, 1, pw1);
        PKSWAP(s1, 0, pw2); PKSWAP(s1, 1, pw3);
        bf16x8 paf[4];
        { uint4 q = { pw0[0], pw0[1], pw0[2], pw0[3] }; paf[0] = __builtin_bit_cast(bf16x8, q); }
        { uint4 q = { pw1[0], pw1[1], pw1[2], pw1[3] }; paf[1] = __builtin_bit_cast(bf16x8, q); }
        { uint4 q = { pw2[0], pw2[1], pw2[2], pw2[3] }; paf[2] = __builtin_bit_cast(bf16x8, q); }
        { uint4 q = { pw3[0], pw3[1], pw3[2], pw3[3] }; paf[3] = __builtin_bit_cast(bf16x8, q); }

        // stage next tile: end-of-iter barrier drain only covers PV
        if (t + 1 < TPB) stage(g0 + t + 1, buf ^ 1);

        // PV: O[m][n'] += P[m][k'] * yT[n'][k']
        const char* tb = lds + 65536 + buf * 32768;
#pragma unroll
        for (int nt = 0; nt < 8; ++nt) {
            int np = nt * 32 + lm;
#pragma unroll
            for (int tpq = 0; tpq < 4; ++tpq) {
                int phys = (hi + 2 * tpq) ^ (np & 7);
                bf16x8 bfr = *(const bf16x8*)(tb + np * 128 + phys * 16);
                o[nt] = __builtin_amdgcn_mfma_f32_32x32x16_bf16(paf[tpq], bfr, o[nt], 0, 0, 0);
            }
        }

        __syncthreads();
    }

    // Z partial (lane pair hi/lo holds complementary j subsets)
    z += __shfl_xor(z, 32, 64);
    if (lane < 32) zpart[(size_t)jc * N + i0 + w * 32 + lane] = z;

    float* ob = (jc == 0) ? o0 : (ows + (size_t)(jc - 1) * N * 256);
#pragma unroll
    for (int nt = 0; nt < 8; ++nt) {
#pragma unroll
        for (int rg = 0; rg < 16; ++rg) {
            int m = (rg & 3) + 8 * (rg >> 2) + 4 * hi;
            ob[(size_t)(i0 + w * 32 + m) * 256 + nt * 32 + lm] = o[nt][rg];
        }
    }
}

// ---------- reductions ----------
__global__ __launch_bounds__(256) void zred(const float* __restrict__ zpart,
                                            float* __restrict__ zinv, int N, int js) {
    int i = blockIdx.x * 256 + threadIdx.x;
    if (i >= N) return;
    float s = 0.0f;
    for (int jc = 0; jc < js; ++jc) s += zpart[(size_t)jc * N + i];
    zinv[i] = 0.5f / s;
}

__global__ __launch_bounds__(256) void fin(float* __restrict__ out,
                                           const float* __restrict__ ows,
                                           const float* __restrict__ zinv,
                                           const float* __restrict__ x,
                                           int N, int js) {
    int gid = blockIdx.x * 256 + threadIdx.x;     // one float4 each
    if (gid >= N * 64) return;
    int i = gid >> 6;
    float4 a = ((const float4*)out)[gid];
    for (int jc = 1; jc < js; ++jc) {
        float4 p = ((const float4*)(ows + (size_t)(jc - 1) * N * 256))[gid];
        a.x += p.x; a.y += p.y; a.z += p.z; a.w += p.w;
    }
    float zi = zinv[i];
    float4 xv = ((const float4*)x)[gid];
    float4 r;
    r.x = a.x * zi + 0.5f * xv.x;
    r.y = a.y * zi + 0.5f * xv.y;
    r.z = a.z * zi + 0.5f * xv.z;
    r.w = a.w * zi + 0.5f * xv.w;
    ((float4*)out)[gid] = r;
}

extern "C" void kernel_launch(void* const* d_in, const int* in_sizes, int n_in,
                              void* d_out, int out_size, void* d_ws, size_t ws_size,
                              hipStream_t stream) {
    const float* x = (const float*)d_in[0];
    const float* y = (const float*)d_in[1];
    const float* adj = (const float*)d_in[2];
    float* out = (float*)d_out;

    const int D = 256;
    int N = in_sizes[0] / D;
    int M = in_sizes[1] / D;

    char* w = (char*)d_ws;
    unsigned short* xhat = (unsigned short*)w;                       // N*512 B
    char* yswz  = w + (size_t)N * 512;                               // M*512 B
    char* ytswz = w + (size_t)N * 512 + (size_t)M * 512;             // M*512 B
    unsigned short* msk = (unsigned short*)(w + (size_t)N * 512 + 2 * (size_t)M * 512);
    size_t base = (size_t)N * 512 + 2 * (size_t)M * 512
                + (size_t)N * (size_t)(M / 16) * 2;                  // + masks

    int js = 1;
    {
        int cands[4] = { 8, 4, 2, 1 };
        for (int k = 0; k < 4; ++k) {
            int c = cands[k];
            size_t need = base + (size_t)(c + 1) * N * 4 +           // zpart + zinv
                          (size_t)(c - 1) * N * 1024;                // O partials
            if (ws_size >= need) { js = c; break; }
        }
    }
    float* zpart = (float*)(w + base);
    float* zinv  = zpart + (size_t)js * N;
    float* ows   = zinv + N;
    int TPB = (M / 64) / js;

    long long mtotal = (long long)N * (M / 16);
    prep_mask<<<2048, 256, 0, stream>>>(adj, msk, mtotal);
    prep_x<<<(N + 3) / 4, 256, 0, stream>>>(x, xhat, N);
    prep_y<<<(M + 3) / 4, 256, 0, stream>>>(y, yswz, M);
    prep_yt<<<((M / 64) * 2048 + 255) / 256, 256, 0, stream>>>(y, ytswz, M);
    gat_main<<<dim3(N / 256, js), 512, 0, stream>>>(xhat, yswz, ytswz,
                                                    (const unsigned long long*)msk,
                                                    out, ows, zpart, N, M, TPB);
    zred<<<(N + 255) / 256, 256, 0, stream>>>(zpart, zinv, N, js);
    fin<<<(N * 64 + 255) / 256, 256, 0, stream>>>(out, ows, zinv, x, N, js);
}

// Round 11
// 231.015 us; speedup vs baseline: 1.7748x; 1.0113x over previous
//
#include <hip/hip_runtime.h>

// GraphAttentionLayer, MI355X (gfx950). All fp32 in/out.
// out = 0.5 * softmax_row(cos(xn,yn) + (1-adj)*NEG) @ y + 0.5 * x
//
// R11 = R10 (bitmask prepass + dense flash-MFMA main, verified) with
// jc->XCD CO-LOCATION: gat_main uses a 1D grid, decoded jc = id % 8,
// bx = id / 8. XCD dispatch is round-robin on id (m09), so all 32 blocks
// sharing a jc (and thus the same 2MB y-tile slice + 1MB mask slice) land
// on ONE XCD -> y stages become L2 hits instead of L3/HBM round trips.
// R10 counters showed 238MB fetch = zero L2 reuse of y tiles; this is the
// one structural fix for it.

typedef short bf16x8 __attribute__((ext_vector_type(8)));
typedef float f32x16 __attribute__((ext_vector_type(16)));

static constexpr float EPSF = 1e-8f;
static constexpr float LOG2E = 1.44269504088896340736f;

__device__ __forceinline__ unsigned short f2bf(float f) {
    union { float f; unsigned int i; } v; v.f = f;
    return (unsigned short)((v.i + 0x7FFFu + ((v.i >> 16) & 1u)) >> 16);
}

// ---------- prepass: adj -> 1-bit masks (u16 per 16 cols) ----------
__global__ __launch_bounds__(256) void prep_mask(const float* __restrict__ adj,
                                                 unsigned short* __restrict__ msk,
                                                 long long total) {  // N*M/16
    long long stride = (long long)gridDim.x * blockDim.x;
    for (long long it = (long long)blockIdx.x * blockDim.x + threadIdx.x;
         it < total; it += stride) {
        const float* ap = adj + it * 16;
        float4 a0 = *(const float4*)(ap + 0);
        float4 a1 = *(const float4*)(ap + 4);
        float4 a2 = *(const float4*)(ap + 8);
        float4 a3 = *(const float4*)(ap + 12);
        unsigned m = 0;
        m |= (a0.x != 0.0f ? 1u : 0u) << 0;  m |= (a0.y != 0.0f ? 1u : 0u) << 1;
        m |= (a0.z != 0.0f ? 1u : 0u) << 2;  m |= (a0.w != 0.0f ? 1u : 0u) << 3;
        m |= (a1.x != 0.0f ? 1u : 0u) << 4;  m |= (a1.y != 0.0f ? 1u : 0u) << 5;
        m |= (a1.z != 0.0f ? 1u : 0u) << 6;  m |= (a1.w != 0.0f ? 1u : 0u) << 7;
        m |= (a2.x != 0.0f ? 1u : 0u) << 8;  m |= (a2.y != 0.0f ? 1u : 0u) << 9;
        m |= (a2.z != 0.0f ? 1u : 0u) << 10; m |= (a2.w != 0.0f ? 1u : 0u) << 11;
        m |= (a3.x != 0.0f ? 1u : 0u) << 12; m |= (a3.y != 0.0f ? 1u : 0u) << 13;
        m |= (a3.z != 0.0f ? 1u : 0u) << 14; m |= (a3.w != 0.0f ? 1u : 0u) << 15;
        msk[it] = (unsigned short)m;
    }
}

// ---------- prepass: xhat (plain row-major normalized bf16) ----------
__global__ __launch_bounds__(256) void prep_x(const float* __restrict__ x,
                                              unsigned short* __restrict__ xhat, int N) {
    int row = (int)((blockIdx.x * blockDim.x + threadIdx.x) >> 6);
    int lane = threadIdx.x & 63;
    if (row >= N) return;
    float4 v = *(const float4*)(x + (size_t)row * 256 + lane * 4);
    float ss = v.x * v.x + v.y * v.y + v.z * v.z + v.w * v.w;
#pragma unroll
    for (int o = 1; o < 64; o <<= 1) ss += __shfl_xor(ss, o, 64);
    float inv = 1.0f / fmaxf(sqrtf(ss), EPSF);
    ushort4 b = { f2bf(v.x * inv), f2bf(v.y * inv), f2bf(v.z * inv), f2bf(v.w * inv) };
    *(ushort4*)(xhat + (size_t)row * 256 + lane * 4) = b;
}

// ---------- prepass: yswz (normalized, tiled+swizzled for QK^T A-frags) ----
__global__ __launch_bounds__(256) void prep_y(const float* __restrict__ y,
                                              char* __restrict__ yswz, int M) {
    int row = (int)((blockIdx.x * blockDim.x + threadIdx.x) >> 6);
    int lane = threadIdx.x & 63;
    if (row >= M) return;
    float4 v = *(const float4*)(y + (size_t)row * 256 + lane * 4);
    float ss = v.x * v.x + v.y * v.y + v.z * v.z + v.w * v.w;
#pragma unroll
    for (int o = 1; o < 64; o <<= 1) ss += __shfl_xor(ss, o, 64);
    float inv = 1.0f / fmaxf(sqrtf(ss), EPSF);
    int jt = row >> 6, r = row & 63;
    int u = lane >> 1, h = lane & 1;           // lane's float4 = half-unit (u,h)
    int phys = u ^ (r & 31);
    ushort4 b = { f2bf(v.x * inv), f2bf(v.y * inv), f2bf(v.z * inv), f2bf(v.w * inv) };
    *(ushort4*)(yswz + (size_t)jt * 32768 + r * 512 + phys * 16 + h * 8) = b;
}

// ---------- prepass: ytswz = bf16(y^T), [jtile][256 n][8 units] swizzled ----
__global__ __launch_bounds__(256) void prep_yt(const float* __restrict__ y,
                                               char* __restrict__ ytswz, int M) {
    int t = blockIdx.x * blockDim.x + threadIdx.x;
    int np = t & 255;
    int up = (t >> 8) & 7;
    int jt = t >> 11;
    if (jt >= (M >> 6)) return;
    const float* yb = y + (size_t)(jt * 64 + up * 8) * 256 + np;
    unsigned w0 = (unsigned)f2bf(yb[0])        | ((unsigned)f2bf(yb[256])  << 16);
    unsigned w1 = (unsigned)f2bf(yb[512])      | ((unsigned)f2bf(yb[768])  << 16);
    unsigned w2 = (unsigned)f2bf(yb[1024])     | ((unsigned)f2bf(yb[1280]) << 16);
    unsigned w3 = (unsigned)f2bf(yb[1536])     | ((unsigned)f2bf(yb[1792]) << 16);
    uint4 out = { w0, w1, w2, w3 };
    *(uint4*)(ytswz + (size_t)jt * 32768 + np * 128 + ((up ^ (np & 7)) << 4)) = out;
}

// ---------- main ----------
#define GLD16(gp, lp) __builtin_amdgcn_global_load_lds( \
    (const __attribute__((address_space(1))) unsigned int*)(gp), \
    (__attribute__((address_space(3))) unsigned int*)(lp), 16, 0, 0)

#define PKSWAP(E, TAU, W) { \
    unsigned X0, X1, Y0, Y1; \
    asm("v_cvt_pk_bf16_f32 %0, %1, %2" : "=v"(X0) : "v"(E[8*TAU+0]), "v"(E[8*TAU+1])); \
    asm("v_cvt_pk_bf16_f32 %0, %1, %2" : "=v"(X1) : "v"(E[8*TAU+2]), "v"(E[8*TAU+3])); \
    asm("v_cvt_pk_bf16_f32 %0, %1, %2" : "=v"(Y0) : "v"(E[8*TAU+4]), "v"(E[8*TAU+5])); \
    asm("v_cvt_pk_bf16_f32 %0, %1, %2" : "=v"(Y1) : "v"(E[8*TAU+6]), "v"(E[8*TAU+7])); \
    asm("v_permlane32_swap_b32 %0, %1" : "+v"(X0), "+v"(Y0)); \
    asm("v_permlane32_swap_b32 %0, %1" : "+v"(X1), "+v"(Y1)); \
    W[0] = X0; W[1] = X1; W[2] = Y0; W[3] = Y1; }

__global__ __launch_bounds__(512, 2) void gat_main(
        const unsigned short* __restrict__ xhat,
        const char* __restrict__ yswz,
        const char* __restrict__ ytswz,
        const unsigned long long* __restrict__ mask64,  // [N][M/64]
        float* __restrict__ o0,     // jc==0 partial (d_out)
        float* __restrict__ ows,    // jc>=1 partials
        float* __restrict__ zpart,
        int N, int M, int TPB, int js) {
    __shared__ __align__(16) char lds[131072];  // Y dbuf 2x32K | Yt dbuf 2x32K

    int tid = threadIdx.x;
    int w = tid >> 6, lane = tid & 63;
    int hi = lane >> 5, lm = lane & 31;
    // jc->XCD co-location: XCD = dispatch_id % 8 (round-robin); decode jc as
    // id % js so all blocks sharing a y-slice land on one XCD when js==8.
    int lid = (int)blockIdx.x;
    int jc = lid % js;
    int i0 = (lid / js) * 256;
    int g0 = jc * TPB;

    // Q-frags: lane holds xhat[i0+w*32+lm][16*kt + 8*hi + 0..7]
    bf16x8 qf[16];
    {
        const char* qb = (const char*)xhat + (size_t)(i0 + w * 32 + lm) * 512 + hi * 16;
#pragma unroll
        for (int kt = 0; kt < 16; ++kt) qf[kt] = *(const bf16x8*)(qb + kt * 32);
    }

    f32x16 o[8];
#pragma unroll
    for (int nt = 0; nt < 8; ++nt) o[nt] = (f32x16)(0.0f);
    float z = 0.0f;

    // stage tile g into buffer b (linear LDS; source pre-swizzled)
    auto stage = [&](int g, int b) {
        const char* ys = yswz + (size_t)g * 32768;
        const char* ts = ytswz + (size_t)g * 32768;
        char* yd = lds + b * 32768;
        char* td = lds + 65536 + b * 32768;
#pragma unroll
        for (int c = 0; c < 4; ++c) {
            int lo = w * 4096 + c * 1024;        // wave-uniform LDS base
            int go = lo + lane * 16;             // per-lane global addr
            GLD16(ys + go, yd + lo);
            GLD16(ts + go, td + lo);
        }
    };

    stage(g0, 0);
    __syncthreads();

    // per-lane mask row: output row (i0 + w*32 + lm); both hi halves same row
    const unsigned long long* mrow = mask64 + (size_t)(i0 + w * 32 + lm) * (M >> 6) + g0;

    for (int t = 0; t < TPB; ++t) {
        int buf = t & 1;
        const char* yb = lds + buf * 32768;

        // issue mask load early; L2 latency hides under QK^T
        unsigned long long m64 = mrow[t];

        // QK^T (swapped): S^T[y-row][x-row] over K=256
        f32x16 s0 = (f32x16)(0.0f), s1 = (f32x16)(0.0f);
#pragma unroll
        for (int kt = 0; kt < 16; ++kt) {
            int phys = (hi + 2 * kt) ^ lm;
            bf16x8 a0 = *(const bf16x8*)(yb + lm * 512 + phys * 16);
            bf16x8 a1 = *(const bf16x8*)(yb + (32 + lm) * 512 + phys * 16);
            s0 = __builtin_amdgcn_mfma_f32_32x32x16_bf16(a0, qf[kt], s0, 0, 0, 0);
            s1 = __builtin_amdgcn_mfma_f32_32x32x16_bf16(a1, qf[kt], s1, 0, 0, 0);
        }

        unsigned mw0 = (unsigned)m64, mw1 = (unsigned)(m64 >> 32);

        // mask + exp(cos-1) + Z, in place into s0/s1
        float zl = 0.0f;
#pragma unroll
        for (int rg = 0; rg < 16; ++rg) {
            int jl = (rg & 3) + 8 * (rg >> 2) + 4 * hi;
            float x0 = __builtin_exp2f(__builtin_fmaf(s0[rg], LOG2E, -LOG2E));
            float x1 = __builtin_exp2f(__builtin_fmaf(s1[rg], LOG2E, -LOG2E));
            s0[rg] = ((mw0 >> jl) & 1u) ? x0 : 0.0f;
            s1[rg] = ((mw1 >> jl) & 1u) ? x1 : 0.0f;
            zl += s0[rg] + s1[rg];
        }
        z += zl;

        // P -> PV A-frags in-register (cvt_pk + permlane32_swap)
        unsigned pw0[4], pw1[4], pw2[4], pw3[4];
        PKSWAP(s0, 0, pw0); PKSWAP(s0, 1, pw1);
        PKSWAP(s1, 0, pw2); PKSWAP(s1, 1, pw3);
        bf16x8 paf[4];
        { uint4 q = { pw0[0], pw0[1], pw0[2], pw0[3] }; paf[0] = __builtin_bit_cast(bf16x8, q); }
        { uint4 q = { pw1[0], pw1[1], pw1[2], pw1[3] }; paf[1] = __builtin_bit_cast(bf16x8, q); }
        { uint4 q = { pw2[0], pw2[1], pw2[2], pw2[3] }; paf[2] = __builtin_bit_cast(bf16x8, q); }
        { uint4 q = { pw3[0], pw3[1], pw3[2], pw3[3] }; paf[3] = __builtin_bit_cast(bf16x8, q); }

        // stage next tile: end-of-iter barrier drain only covers PV
        if (t + 1 < TPB) stage(g0 + t + 1, buf ^ 1);

        // PV: O[m][n'] += P[m][k'] * yT[n'][k']
        const char* tb = lds + 65536 + buf * 32768;
#pragma unroll
        for (int nt = 0; nt < 8; ++nt) {
            int np = nt * 32 + lm;
#pragma unroll
            for (int tpq = 0; tpq < 4; ++tpq) {
                int phys = (hi + 2 * tpq) ^ (np & 7);
                bf16x8 bfr = *(const bf16x8*)(tb + np * 128 + phys * 16);
                o[nt] = __builtin_amdgcn_mfma_f32_32x32x16_bf16(paf[tpq], bfr, o[nt], 0, 0, 0);
            }
        }

        __syncthreads();
    }

    // Z partial (lane pair hi/lo holds complementary j subsets)
    z += __shfl_xor(z, 32, 64);
    if (lane < 32) zpart[(size_t)jc * N + i0 + w * 32 + lane] = z;

    float* ob = (jc == 0) ? o0 : (ows + (size_t)(jc - 1) * N * 256);
#pragma unroll
    for (int nt = 0; nt < 8; ++nt) {
#pragma unroll
        for (int rg = 0; rg < 16; ++rg) {
            int m = (rg & 3) + 8 * (rg >> 2) + 4 * hi;
            ob[(size_t)(i0 + w * 32 + m) * 256 + nt * 32 + lm] = o[nt][rg];
        }
    }
}

// ---------- reductions ----------
__global__ __launch_bounds__(256) void zred(const float* __restrict__ zpart,
                                            float* __restrict__ zinv, int N, int js) {
    int i = blockIdx.x * 256 + threadIdx.x;
    if (i >= N) return;
    float s = 0.0f;
    for (int jc = 0; jc < js; ++jc) s += zpart[(size_t)jc * N + i];
    zinv[i] = 0.5f / s;
}

__global__ __launch_bounds__(256) void fin(float* __restrict__ out,
                                           const float* __restrict__ ows,
                                           const float* __restrict__ zinv,
                                           const float* __restrict__ x,
                                           int N, int js) {
    int gid = blockIdx.x * 256 + threadIdx.x;     // one float4 each
    if (gid >= N * 64) return;
    int i = gid >> 6;
    float4 a = ((const float4*)out)[gid];
    for (int jc = 1; jc < js; ++jc) {
        float4 p = ((const float4*)(ows + (size_t)(jc - 1) * N * 256))[gid];
        a.x += p.x; a.y += p.y; a.z += p.z; a.w += p.w;
    }
    float zi = zinv[i];
    float4 xv = ((const float4*)x)[gid];
    float4 r;
    r.x = a.x * zi + 0.5f * xv.x;
    r.y = a.y * zi + 0.5f * xv.y;
    r.z = a.z * zi + 0.5f * xv.z;
    r.w = a.w * zi + 0.5f * xv.w;
    ((float4*)out)[gid] = r;
}

extern "C" void kernel_launch(void* const* d_in, const int* in_sizes, int n_in,
                              void* d_out, int out_size, void* d_ws, size_t ws_size,
                              hipStream_t stream) {
    const float* x = (const float*)d_in[0];
    const float* y = (const float*)d_in[1];
    const float* adj = (const float*)d_in[2];
    float* out = (float*)d_out;

    const int D = 256;
    int N = in_sizes[0] / D;
    int M = in_sizes[1] / D;

    char* w = (char*)d_ws;
    unsigned short* xhat = (unsigned short*)w;                       // N*512 B
    char* yswz  = w + (size_t)N * 512;                               // M*512 B
    char* ytswz = w + (size_t)N * 512 + (size_t)M * 512;             // M*512 B
    unsigned short* msk = (unsigned short*)(w + (size_t)N * 512 + 2 * (size_t)M * 512);
    size_t base = (size_t)N * 512 + 2 * (size_t)M * 512
                + (size_t)N * (size_t)(M / 16) * 2;                  // + masks

    int js = 1;
    {
        int cands[4] = { 8, 4, 2, 1 };
        for (int k = 0; k < 4; ++k) {
            int c = cands[k];
            size_t need = base + (size_t)(c + 1) * N * 4 +           // zpart + zinv
                          (size_t)(c - 1) * N * 1024;                // O partials
            if (ws_size >= need) { js = c; break; }
        }
    }
    float* zpart = (float*)(w + base);
    float* zinv  = zpart + (size_t)js * N;
    float* ows   = zinv + N;
    int TPB = (M / 64) / js;

    long long mtotal = (long long)N * (M / 16);
    prep_mask<<<2048, 256, 0, stream>>>(adj, msk, mtotal);
    prep_x<<<(N + 3) / 4, 256, 0, stream>>>(x, xhat, N);
    prep_y<<<(M + 3) / 4, 256, 0, stream>>>(y, yswz, M);
    prep_yt<<<((M / 64) * 2048 + 255) / 256, 256, 0, stream>>>(y, ytswz, M);
    gat_main<<<(N / 256) * js, 512, 0, stream>>>(xhat, yswz, ytswz,
                                                 (const unsigned long long*)msk,
                                                 out, ows, zpart, N, M, TPB, js);
    zred<<<(N + 255) / 256, 256, 0, stream>>>(zpart, zinv, N, js);
    fin<<<(N * 64 + 255) / 256, 256, 0, stream>>>(out, ows, zinv, x, N, js);
}